// Round 1
// baseline (288.411 us; speedup 1.0000x reference)
//
#include <hip/hip_runtime.h>
#include <stdint.h>

typedef __attribute__((ext_vector_type(8))) short short8;
typedef __attribute__((ext_vector_type(4))) float f32x4;

#define B_ 8
#define C_ 64
#define N_ 4096

__device__ __forceinline__ unsigned short f2bf(float f) {
  unsigned int u = __float_as_uint(f);
  u = (u + 0x7fffu + ((u >> 16) & 1u)) >> 16;
  return (unsigned short)u;
}

// x: [B, C, N] fp32 (N = H*W). t[b,n,c] = x[b,c,n].
// q[b,n,o] = sum_c x[b,c,n] * W[o,c] + bias[o]
// Writes q,k row-major [B][N][64] bf16; v transposed [B][64][N] bf16.
__global__ __launch_bounds__(256) void qkv_proj(
    const float* __restrict__ x,
    const float* __restrict__ Wq, const float* __restrict__ bq,
    const float* __restrict__ Wk, const float* __restrict__ bk,
    const float* __restrict__ Wv, const float* __restrict__ bv,
    unsigned short* __restrict__ qo, unsigned short* __restrict__ ko,
    unsigned short* __restrict__ vto) {
  const int n = blockIdx.x * 256 + threadIdx.x;
  const int m = blockIdx.y;  // 0=q, 1=k, 2=v(transposed)
  const int b = blockIdx.z;
  const float* W = (m == 0) ? Wq : (m == 1) ? Wk : Wv;
  const float* bi = (m == 0) ? bq : (m == 1) ? bk : bv;

  float xv[64];
  const float* xp = x + (size_t)b * C_ * N_ + n;
#pragma unroll
  for (int c = 0; c < 64; ++c) xv[c] = xp[(size_t)c * N_];

  if (m < 2) {
    unsigned short* dst = ((m == 0) ? qo : ko) + ((size_t)b * N_ + n) * 64;
    for (int o8 = 0; o8 < 8; ++o8) {
      short8 res;
#pragma unroll
      for (int oo = 0; oo < 8; ++oo) {
        const int o = o8 * 8 + oo;
        float a = bi[o];
        const float* wr = W + o * 64;  // wave-uniform -> scalar loads
#pragma unroll
        for (int c = 0; c < 64; ++c) a = fmaf(xv[c], wr[c], a);
        res[oo] = (short)f2bf(a);
      }
      *(short8*)(dst + o8 * 8) = res;  // 16B per lane, lane-contiguous rows
    }
  } else {
    unsigned short* dst = vto + (size_t)b * C_ * N_ + n;
    for (int o8 = 0; o8 < 8; ++o8) {
#pragma unroll
      for (int oo = 0; oo < 8; ++oo) {
        const int o = o8 * 8 + oo;
        float a = bi[o];
        const float* wr = W + o * 64;
#pragma unroll
        for (int c = 0; c < 64; ++c) a = fmaf(xv[c], wr[c], a);
        dst[(size_t)o * N_] = f2bf(a);  // coalesced across lanes (consecutive n)
      }
    }
  }
}

// Flash attention: block = 4 waves, wave w owns 16 Q-rows. 64 KV tiles of 64.
// MFMA 16x16x32 bf16 layouts (gfx950):
//   A[row][kk]: row = lane&15, kk = (lane>>4)*8 + j  (8 contiguous bf16/lane)
//   B[kk][col]: col = lane&15, kk = (lane>>4)*8 + j
//   C/D[row][col]: col = lane&15, row = (lane>>4)*4 + reg
__global__ __launch_bounds__(256) void flash_attn(
    const unsigned short* __restrict__ q,
    const unsigned short* __restrict__ k,
    const unsigned short* __restrict__ vt,
    float* __restrict__ out) {
  const int b = blockIdx.y;
  const int w = threadIdx.x >> 6;
  const int lane = threadIdx.x & 63;
  const int r = lane & 15;
  const int g = lane >> 4;
  const int qrow0 = blockIdx.x * 64 + w * 16;

  // wave-private P staging buffer; rows padded to 72 (144 B: 16B-aligned, bank-spread)
  __shared__ __align__(16) unsigned short pbuf[4][16][72];
  unsigned short(*pb)[72] = pbuf[w];

  const unsigned short* qp = q + ((size_t)b * N_ + qrow0 + r) * 64 + g * 8;
  short8 aq0 = *(const short8*)(qp);       // k-chunk 0 (c 0..31)
  short8 aq1 = *(const short8*)(qp + 32);  // k-chunk 1 (c 32..63)

  f32x4 o[4];
  float m_[4], l_[4];
#pragma unroll
  for (int j = 0; j < 4; ++j) o[j] = (f32x4){0.f, 0.f, 0.f, 0.f};
#pragma unroll
  for (int i = 0; i < 4; ++i) { m_[i] = -3.0e38f; l_[i] = 0.f; }

  const unsigned short* kb = k + (size_t)b * N_ * 64;
  const unsigned short* vb = vt + (size_t)b * 64 * N_;
  const float sc = 0.18033688011112042f;  // (1/sqrt(64)) * log2(e)

  for (int kt = 0; kt < 64; ++kt) {
    const int kv0 = kt * 64;
    short8 bkf[4][2], bvf[4][2];
#pragma unroll
    for (int jt = 0; jt < 4; ++jt) {
      const unsigned short* kr = kb + (size_t)(kv0 + jt * 16 + r) * 64 + g * 8;
      bkf[jt][0] = *(const short8*)(kr);
      bkf[jt][1] = *(const short8*)(kr + 32);
      const unsigned short* vr = vb + (size_t)(jt * 16 + r) * N_ + kv0 + g * 8;
      bvf[jt][0] = *(const short8*)(vr);
      bvf[jt][1] = *(const short8*)(vr + 32);
    }
    // S = Q K^T  (raw, scale folded into exp2 domain)
    f32x4 s[4];
#pragma unroll
    for (int jt = 0; jt < 4; ++jt) {
      f32x4 z = (f32x4){0.f, 0.f, 0.f, 0.f};
      z = __builtin_amdgcn_mfma_f32_16x16x32_bf16(aq0, bkf[jt][0], z, 0, 0, 0);
      s[jt] = __builtin_amdgcn_mfma_f32_16x16x32_bf16(aq1, bkf[jt][1], z, 0, 0, 0);
    }
    // online softmax; lane holds rows g*4+i, col r (per jt tile)
    float mx[4];
#pragma unroll
    for (int i = 0; i < 4; ++i)
      mx[i] = fmaxf(fmaxf(s[0][i], s[1][i]), fmaxf(s[2][i], s[3][i]));
#pragma unroll
    for (int d = 1; d < 16; d <<= 1)
#pragma unroll
      for (int i = 0; i < 4; ++i) mx[i] = fmaxf(mx[i], __shfl_xor(mx[i], d));

    float mn[4], al[4], rs[4];
#pragma unroll
    for (int i = 0; i < 4; ++i) {
      mn[i] = fmaxf(m_[i], mx[i] * sc);
      al[i] = __builtin_amdgcn_exp2f(m_[i] - mn[i]);  // first iter: exp2(-inf)=0
      m_[i] = mn[i];
      rs[i] = 0.f;
    }
    float p[4][4];
#pragma unroll
    for (int jt = 0; jt < 4; ++jt)
#pragma unroll
      for (int i = 0; i < 4; ++i) {
        float pv = __builtin_amdgcn_exp2f(fmaf(s[jt][i], sc, -mn[i]));
        p[jt][i] = pv;
        rs[i] += pv;
      }
#pragma unroll
    for (int d = 1; d < 16; d <<= 1)
#pragma unroll
      for (int i = 0; i < 4; ++i) rs[i] += __shfl_xor(rs[i], d);
#pragma unroll
    for (int i = 0; i < 4; ++i) l_[i] = l_[i] * al[i] + rs[i];
#pragma unroll
    for (int jt = 0; jt < 4; ++jt)
#pragma unroll
      for (int i = 0; i < 4; ++i) o[jt][i] *= al[i];

    // P (C-layout) -> bf16 A-layout via wave-private LDS transpose
#pragma unroll
    for (int jt = 0; jt < 4; ++jt)
#pragma unroll
      for (int i = 0; i < 4; ++i) pb[g * 4 + i][jt * 16 + r] = f2bf(p[jt][i]);
    asm volatile("s_waitcnt lgkmcnt(0)" ::: "memory");
    short8 pa0 = *(const short8*)(&pb[r][g * 8]);
    short8 pa1 = *(const short8*)(&pb[r][32 + g * 8]);
#pragma unroll
    for (int jt = 0; jt < 4; ++jt) {
      o[jt] = __builtin_amdgcn_mfma_f32_16x16x32_bf16(pa0, bvf[jt][0], o[jt], 0, 0, 0);
      o[jt] = __builtin_amdgcn_mfma_f32_16x16x32_bf16(pa1, bvf[jt][1], o[jt], 0, 0, 0);
    }
  }

  float inv[4];
#pragma unroll
  for (int i = 0; i < 4; ++i) inv[i] = 1.f / l_[i];
  // out[b][c][n] = O[n][c] / l[n]
  float* ob = out + (size_t)b * 64 * N_;
#pragma unroll
  for (int jt = 0; jt < 4; ++jt)
#pragma unroll
    for (int i = 0; i < 4; ++i)
      ob[(size_t)(jt * 16 + r) * N_ + qrow0 + g * 4 + i] = o[jt][i] * inv[i];
}

extern "C" void kernel_launch(void* const* d_in, const int* in_sizes, int n_in,
                              void* d_out, int out_size, void* d_ws, size_t ws_size,
                              hipStream_t stream) {
  const float* x  = (const float*)d_in[0];
  const float* Wq = (const float*)d_in[1];
  const float* bq = (const float*)d_in[2];
  const float* Wk = (const float*)d_in[3];
  const float* bk = (const float*)d_in[4];
  const float* Wv = (const float*)d_in[5];
  const float* bv = (const float*)d_in[6];
  float* out = (float*)d_out;

  unsigned short* qws = (unsigned short*)d_ws;          // [B][N][64] bf16
  unsigned short* kws = qws + (size_t)B_ * N_ * 64;     // [B][N][64] bf16
  unsigned short* vws = kws + (size_t)B_ * N_ * 64;     // [B][64][N] bf16 (transposed)

  dim3 gp(N_ / 256, 3, B_);
  qkv_proj<<<gp, 256, 0, stream>>>(x, Wq, bq, Wk, bk, Wv, bv, qws, kws, vws);

  dim3 ga(N_ / 64, B_);
  flash_attn<<<ga, 256, 0, stream>>>(qws, kws, vws, out);
}